// Round 16
// baseline (108.212 us; speedup 1.0000x reference)
//
#include <hip/hip_runtime.h>
#include <hip/hip_bf16.h>
#include <stdint.h>

#define B_ 64
#define N_ 1024
#define D_ 128

typedef __attribute__((ext_vector_type(8))) short bf16x8;
typedef __attribute__((ext_vector_type(4))) float f32x4;
typedef __attribute__((ext_vector_type(2))) unsigned int uint32x2;

__device__ __forceinline__ unsigned short f2bf(float f) {
    union { float f; uint32_t u; } v; v.f = f;
    uint32_t u = v.u;
    return (unsigned short)((u + 0x7FFFu + ((u >> 16) & 1u)) >> 16);
}

// Device-scope arrive-and-spin global barrier. Safe: grid = 256 blocks at
// 1 block/CU (143KB LDS) on a 256-CU chip -> all blocks co-resident.
__device__ __forceinline__ void gbar(int* c, int target) {
    __syncthreads();
    if (threadIdx.x == 0) {
        __threadfence();                       // publish my phase's writes
        atomicAdd(c, 1);
        while (atomicAdd(c, 0) < target) __builtin_amdgcn_s_sleep(2);
        __threadfence();                       // acquire others' writes
    }
    __syncthreads();
}

// ---------------------------------------------------------------------------
// Fused persistent kernel: phase W (wtrans) -> gbar -> phase P (proj, 2 tiles
// at a time via 256-thread halves) -> gbar -> phase A (attn, r15 datapath).
__global__ __launch_bounds__(512, 1) void mega_kernel(
    const float* __restrict__ x,
    const float* __restrict__ Wq, const float* __restrict__ bq,
    const float* __restrict__ Wk, const float* __restrict__ bk,
    const float* __restrict__ Wv, const float* __restrict__ bv,
    const int* __restrict__ valid_lens,
    unsigned short* __restrict__ wt,
    unsigned short* __restrict__ qg, unsigned short* __restrict__ kg,
    unsigned short* __restrict__ vtg,
    float* __restrict__ out, int* __restrict__ ctr)
{
    __shared__ alignas(16) unsigned short smem[71680];
    __shared__ int slot;

    const int tid = threadIdx.x;
    const f32x4 zero4 = {0.f, 0.f, 0.f, 0.f};

    // ---------------- Phase W: W (f32 [k][d]) -> bf16 W^T [d][k] -----------
    if (blockIdx.x < 48) {
        int p = blockIdx.x >> 4, seg = blockIdx.x & 15;
        const float* W = (p == 0) ? Wq : (p == 1) ? Wk : Wv;
        unsigned short* dst = wt + p * (D_ * D_);
        #pragma unroll
        for (int i = 0; i < 2; ++i) {
            int idx = seg * 1024 + i * 512 + tid;
            int k = idx >> 7, d = idx & 127;
            dst[d * D_ + k] = f2bf(W[idx]);
        }
    }
    gbar(ctr + 1, 256);

    // ---------------- Phase P: QKV projection (4 tiles, 2 per round) -------
    {
        const int half = tid >> 8, t256 = tid & 255;
        unsigned short* const xs = smem + half * 26112;           // [64][136]
        unsigned short* const ws = smem + half * 26112 + 8704;    // [128][136]
        const int pwave = t256 >> 6, plane = t256 & 63;
        const int lr = plane & 15, lg = plane >> 4;

        for (int j = 0; j < 2; ++j) {
            const int T = blockIdx.x + 256 * half + 512 * j;      // tile 0..1023
            const int row0 = T * 64;
            const int b = T >> 4, n0 = row0 & 1023;
            const bool act = (n0 < valid_lens[b]);

            if (act) {
                for (int it = 0; it < 8; ++it) {
                    int idx4 = it * 256 + t256;
                    int r = idx4 >> 5, c4 = (idx4 & 31) * 4;
                    const float4 v = *(const float4*)&x[(size_t)(row0 + r) * D_ + c4];
                    unsigned short tmp[4] = { f2bf(v.x), f2bf(v.y), f2bf(v.z), f2bf(v.w) };
                    *(uint2*)&xs[r * 136 + c4] = *(uint2*)tmp;
                }
            }

            for (int p = 0; p < 3; ++p) {
                __syncthreads();   // xs ready / prior ws uses done
                if (act) {
                    const unsigned short* wsrc = wt + p * (D_ * D_);
                    for (int it = 0; it < 8; ++it) {
                        int idx8 = it * 256 + t256;
                        int r = idx8 >> 4, c8 = (idx8 & 15) * 8;
                        *(bf16x8*)&ws[r * 136 + c8] = *(const bf16x8*)&wsrc[idx8 * 8];
                    }
                }
                __syncthreads();   // ws (W^T) ready

                f32x4 acc[8];
                if (act) {
                    bf16x8 a[4];
                    for (int kk = 0; kk < 4; ++kk)
                        a[kk] = *(const bf16x8*)&xs[(pwave * 16 + lr) * 136 + kk * 32 + lg * 8];
                    for (int nt = 0; nt < 8; ++nt) acc[nt] = zero4;
                    for (int kk = 0; kk < 4; ++kk)
                        for (int nt = 0; nt < 8; ++nt) {
                            bf16x8 bfr = *(const bf16x8*)&ws[(nt * 16 + lr) * 136 + kk * 32 + lg * 8];
                            acc[nt] = __builtin_amdgcn_mfma_f32_16x16x32_bf16(a[kk], bfr, acc[nt], 0, 0, 0);
                        }
                }
                __syncthreads();   // all waves done reading ws (W^T)

                if (p < 2) {
                    if (act) {
                        const float* bias = (p == 0) ? bq : bk;
                        // q: 1/sqrt(128) * log2(e) folded (exp2-native softmax)
                        const float sc = (p == 0) ? 0.12751741388f : 1.0f;
                        for (int nt = 0; nt < 8; ++nt) {
                            int d = nt * 16 + lr;
                            float bb = bias[d];
                            for (int r = 0; r < 4; ++r)
                                ws[(pwave * 16 + lg * 4 + r) * 136 + d] = f2bf((acc[nt][r] + bb) * sc);
                        }
                    }
                    __syncthreads();
                    if (act) {
                        unsigned short* outp = (p == 0) ? qg : kg;
                        for (int it = 0; it < 4; ++it) {
                            int idx = it * 256 + t256;
                            int r = idx >> 4, c8 = (idx & 15) * 8;
                            *(bf16x8*)&outp[(size_t)(row0 + r) * D_ + c8] =
                                *(const bf16x8*)&ws[r * 136 + c8];
                        }
                    }
                } else {
                    if (act) {
                        for (int nt = 0; nt < 8; ++nt) {
                            int d = nt * 16 + lr;
                            float bb = bv[d];
                            for (int r = 0; r < 4; ++r)
                                ws[d * 72 + pwave * 16 + lg * 4 + r] = f2bf(acc[nt][r] + bb);
                        }
                    }
                    __syncthreads();
                    if (act) {
                        unsigned short* dst = vtg + ((size_t)b * D_) * N_ + n0;
                        for (int it = 0; it < 4; ++it) {
                            int idx = it * 256 + t256;
                            int d = idx >> 3, c8 = (idx & 7) * 8;
                            *(bf16x8*)&dst[(size_t)d * N_ + c8] = *(const bf16x8*)&ws[d * 72 + c8];
                        }
                    }
                }
            }
        }
    }
    gbar(ctr + 1, 512);

    // ---------------- Phase A: persistent flash attention (r15) ------------
    const int wave = tid >> 6, lane = tid & 63;
    const int lr = lane & 15, lg = lane >> 4;
    const int grp = tid >> 8;            // 0: waves 0-3, 1: waves 4-7
    const int wg = wave & 3;             // q-row group within the item
    const int t256 = tid & 255;
    const int k_r = t256 >> 4, k_c = (t256 & 15) * 8;
    const int v_d = t256 >> 3, v_c = (t256 & 7) * 8;
    unsigned short* const ks_base = smem + grp * 17408;          // 2 bufs of 8704
    unsigned short* const vt_base = smem + 34816 + grp * 18432;  // 2 bufs of 9216
    float* const cmbF = (float*)smem;    // f32x4 combine slots (dead ks/vt alias)
    const bool hbit = (lg >> 1) != 0;    // lane & 32
    const bool mbit = (lg & 1) != 0;     // lane & 16

    int item = blockIdx.x;
    while (item < 512) {
        const int qt = 7 - (item >> 6);           // heavy (high-qt) items first
        const int b  = item & 63;
        const int L  = valid_lens[b];
        const int q0 = qt * 128;
        float* outb = out + ((size_t)b * N_ + q0) * D_;

        if (q0 >= L) {
            #pragma unroll
            for (int it = 0; it < 8; ++it) {
                int idx4 = it * 512 + tid;
                int r = idx4 >> 5, c4 = (idx4 & 31) * 4;
                float4 z; z.x = z.y = z.z = z.w = 0.f;
                *(float4*)&outb[(size_t)r * D_ + c4] = z;
            }
        } else {
            const int ntiles = (L + 63) >> 6;
            const int H = (ntiles + 1) >> 1;
            const int myStart = grp ? H : 0;
            const int myCnt = grp ? (ntiles - H) : H;
            const unsigned short* kgb = kg + (size_t)b * N_ * D_;
            const unsigned short* vtb = vtg + (size_t)b * D_ * N_;

            bf16x8 aq[2][4];
            #pragma unroll
            for (int rt = 0; rt < 2; ++rt) {
                const unsigned short* qrow =
                    qg + ((size_t)b * N_ + q0 + wg * 32 + rt * 16 + lr) * D_;
                #pragma unroll
                for (int kk = 0; kk < 4; ++kk)
                    aq[rt][kk] = *(const bf16x8*)&qrow[kk * 32 + lg * 8];
            }

            f32x4 oacc[2][8];
            #pragma unroll
            for (int rt = 0; rt < 2; ++rt)
                #pragma unroll
                for (int i = 0; i < 8; ++i) oacc[rt][i] = zero4;
            float lsum[2] = {0.f, 0.f};

            bf16x8 kreg[4], vreg[4];

            if (myCnt > 0) {
                const int kv0 = myStart * 64;
                #pragma unroll
                for (int it = 0; it < 4; ++it)
                    kreg[it] = *(const bf16x8*)&kgb[(size_t)(kv0 + it * 16 + k_r) * D_ + k_c];
                #pragma unroll
                for (int it = 0; it < 4; ++it)
                    vreg[it] = *(const bf16x8*)&vtb[(size_t)(it * 32 + v_d) * N_ + kv0 + v_c];
                #pragma unroll
                for (int it = 0; it < 4; ++it)
                    *(bf16x8*)&ks_base[(it * 16 + k_r) * 136 + k_c] = kreg[it];
                #pragma unroll
                for (int it = 0; it < 4; ++it)
                    *(bf16x8*)&vt_base[(it * 32 + v_d) * 72 + v_c] = vreg[it];
            }
            __syncthreads();

            for (int r = 0; r < H; ++r) {
                const bool valid = (r < myCnt);
                const int kv0 = (myStart + r) * 64;
                const int ko_cur = (r & 1) ? 8704 : 0;
                const int vo_cur = (r & 1) ? 9216 : 0;
                unsigned short* const ks_my = ks_base + ko_cur;
                unsigned short* const vt_my = vt_base + vo_cur;

                if (r + 1 < myCnt) {
                    const int kvn = kv0 + 64;
                    #pragma unroll
                    for (int it = 0; it < 4; ++it)
                        kreg[it] = *(const bf16x8*)&kgb[(size_t)(kvn + it * 16 + k_r) * D_ + k_c];
                    #pragma unroll
                    for (int it = 0; it < 4; ++it)
                        vreg[it] = *(const bf16x8*)&vtb[(size_t)(it * 32 + v_d) * N_ + kvn + v_c];
                    __builtin_amdgcn_sched_barrier(0);
                }

                if (valid) {
                    f32x4 s[2][4];
                    __builtin_amdgcn_s_setprio(1);
                    #pragma unroll
                    for (int nt = 0; nt < 4; ++nt) {
                        s[0][nt] = zero4; s[1][nt] = zero4;
                        #pragma unroll
                        for (int kk = 0; kk < 4; ++kk) {
                            bf16x8 bk_ = *(const bf16x8*)&ks_my[(nt * 16 + lr) * 136 + kk * 32 + lg * 8];
                            s[0][nt] = __builtin_amdgcn_mfma_f32_16x16x32_bf16(bk_, aq[0][kk], s[0][nt], 0, 0, 0);
                            s[1][nt] = __builtin_amdgcn_mfma_f32_16x16x32_bf16(bk_, aq[1][kk], s[1][nt], 0, 0, 0);
                        }
                    }
                    __builtin_amdgcn_s_setprio(0);

                    uint32_t pwv[2][8];
                    if (kv0 + 64 <= L) {
                        #pragma unroll
                        for (int nt = 0; nt < 4; ++nt)
                            #pragma unroll
                            for (int rt = 0; rt < 2; ++rt) {
                                float e0 = __builtin_amdgcn_exp2f(s[rt][nt][0]);
                                float e1 = __builtin_amdgcn_exp2f(s[rt][nt][1]);
                                float e2 = __builtin_amdgcn_exp2f(s[rt][nt][2]);
                                float e3 = __builtin_amdgcn_exp2f(s[rt][nt][3]);
                                lsum[rt] += (e0 + e1) + (e2 + e3);
                                uint32_t w0, w1;
                                asm("v_cvt_pk_bf16_f32 %0, %1, %2" : "=v"(w0) : "v"(e0), "v"(e1));
                                asm("v_cvt_pk_bf16_f32 %0, %1, %2" : "=v"(w1) : "v"(e2), "v"(e3));
                                pwv[rt][nt * 2 + 0] = w0;
                                pwv[rt][nt * 2 + 1] = w1;
                            }
                    } else {
                        #pragma unroll
                        for (int nt = 0; nt < 4; ++nt) {
                            const int kvb = kv0 + nt * 16 + lg * 4;
                            #pragma unroll
                            for (int rt = 0; rt < 2; ++rt) {
                                float e0 = (kvb + 0 < L) ? __builtin_amdgcn_exp2f(s[rt][nt][0]) : 0.f;
                                float e1 = (kvb + 1 < L) ? __builtin_amdgcn_exp2f(s[rt][nt][1]) : 0.f;
                                float e2 = (kvb + 2 < L) ? __builtin_amdgcn_exp2f(s[rt][nt][2]) : 0.f;
                                float e3 = (kvb + 3 < L) ? __builtin_amdgcn_exp2f(s[rt][nt][3]) : 0.f;
                                lsum[rt] += (e0 + e1) + (e2 + e3);
                                uint32_t w0, w1;
                                asm("v_cvt_pk_bf16_f32 %0, %1, %2" : "=v"(w0) : "v"(e0), "v"(e1));
                                asm("v_cvt_pk_bf16_f32 %0, %1, %2" : "=v"(w1) : "v"(e2), "v"(e3));
                                pwv[rt][nt * 2 + 0] = w0;
                                pwv[rt][nt * 2 + 1] = w1;
                            }
                        }
                    }

                    #pragma unroll
                    for (int rt = 0; rt < 2; ++rt) {
                        uint32_t sh[4], so[4];
                        #pragma unroll
                        for (int i = 0; i < 4; ++i) {
                            int i0 = (i >> 1) * 4 + (i & 1);
                            sh[i] = hbit ? pwv[rt][i0 + 2] : pwv[rt][i0];
                            so[i] = hbit ? pwv[rt][i0] : pwv[rt][i0 + 2];
                        }
                        uint32_t rv[4];
                        #pragma unroll
                        for (int i = 0; i < 4; ++i) {
#if __has_builtin(__builtin_amdgcn_permlane32_swap)
                            uint32x2 pr = __builtin_amdgcn_permlane32_swap(so[i], so[i], false, false);
                            rv[i] = hbit ? pr[0] : pr[1];
#else
                            rv[i] = (uint32_t)__shfl_xor((int)so[i], 32);
#endif
                        }
                        const bool c2 = (hbit != mbit);
                        uint32_t s2[4], kp[4];
                        #pragma unroll
                        for (int i = 0; i < 4; ++i) {
                            s2[i] = c2 ? sh[i] : rv[i];
                            kp[i] = c2 ? rv[i] : sh[i];
                        }
                        uint32_t r2v[4];
                        #pragma unroll
                        for (int i = 0; i < 4; ++i) {
#if __has_builtin(__builtin_amdgcn_permlane16_swap)
                            uint32x2 qr = __builtin_amdgcn_permlane16_swap(s2[i], s2[i], false, false);
                            r2v[i] = mbit ? qr[0] : qr[1];
#else
                            r2v[i] = (uint32_t)__shfl_xor((int)s2[i], 16);
#endif
                        }
                        uint32_t apw[2][4];
                        #pragma unroll
                        for (int kk = 0; kk < 2; ++kk)
                            #pragma unroll
                            for (int c = 0; c < 2; ++c) {
                                uint32_t kw = kp[kk * 2 + c], rw = r2v[kk * 2 + c];
                                apw[kk][c]     = mbit ? rw : kw;
                                apw[kk][2 + c] = mbit ? kw : rw;
                            }
                        __builtin_amdgcn_s_setprio(1);
                        #pragma unroll
                        for (int kk = 0; kk < 2; ++kk) {
                            bf16x8 ap = *(bf16x8*)&apw[kk][0];
                            #pragma unroll
                            for (int nt = 0; nt < 8; ++nt) {
                                bf16x8 bv_ = *(const bf16x8*)&vt_my[(nt * 16 + lr) * 72 + kk * 32 + lg * 8];
                                oacc[rt][nt] = __builtin_amdgcn_mfma_f32_16x16x32_bf16(ap, bv_, oacc[rt][nt], 0, 0, 0);
                            }
                        }
                        __builtin_amdgcn_s_setprio(0);
                    }
                }

                if (r + 1 < myCnt) {
                    unsigned short* const ks_nx = ks_base + (ko_cur ^ 8704);
                    unsigned short* const vt_nx = vt_base + (vo_cur ^ 9216);
                    #pragma unroll
                    for (int it = 0; it < 4; ++it)
                        *(bf16x8*)&ks_nx[(it * 16 + k_r) * 136 + k_c] = kreg[it];
                    #pragma unroll
                    for (int it = 0; it < 4; ++it)
                        *(bf16x8*)&vt_nx[(it * 32 + v_d) * 72 + v_c] = vreg[it];
                }
                __syncthreads();
            }

            #pragma unroll
            for (int rt = 0; rt < 2; ++rt) {
                float l = lsum[rt];
                l += __shfl_xor(l, 16);
                l += __shfl_xor(l, 32);
                lsum[rt] = l;
            }

            if (grp == 1) {
                #pragma unroll
                for (int rt = 0; rt < 2; ++rt) {
                    if (lg == 0) cmbF[17408 + wg * 32 + rt * 16 + lr] = lsum[rt];
                    #pragma unroll
                    for (int nt = 0; nt < 8; ++nt)
                        *(f32x4*)&cmbF[(t256 * 17 + rt * 8 + nt) * 4] = oacc[rt][nt];
                }
            }
            __syncthreads();
            if (grp == 0) {
                #pragma unroll
                for (int rt = 0; rt < 2; ++rt) {
                    const int qrow = q0 + wg * 32 + rt * 16 + lr;
                    float tot = lsum[rt] + cmbF[17408 + wg * 32 + rt * 16 + lr];
                    float invq = (qrow < L) ? 1.0f / tot : 0.0f;
                    f32x4 part[8];
                    #pragma unroll
                    for (int nt = 0; nt < 8; ++nt)
                        part[nt] = *(const f32x4*)&cmbF[(t256 * 17 + rt * 8 + nt) * 4];
                    #pragma unroll
                    for (int r2 = 0; r2 < 4; ++r2) {
                        const float invr = __shfl(invq, lg * 4 + r2);
                        const int row = wg * 32 + rt * 16 + lg * 4 + r2;
                        #pragma unroll
                        for (int nt = 0; nt < 8; ++nt) {
                            const int col = nt * 16 + lr;
                            outb[(size_t)row * D_ + col] =
                                (oacc[rt][nt][r2] + part[nt][r2]) * invr;
                        }
                    }
                }
            }
            __syncthreads();
        }

        if (tid == 0) slot = 256 + atomicAdd(ctr, 1);
        __syncthreads();
        item = slot;
        __syncthreads();
    }
}

// ---------------------------------------------------------------------------
extern "C" void kernel_launch(void* const* d_in, const int* in_sizes, int n_in,
                              void* d_out, int out_size, void* d_ws, size_t ws_size,
                              hipStream_t stream) {
    const float* x    = (const float*)d_in[0];
    const int*   vlen = (const int*)d_in[1];
    const float* Wq   = (const float*)d_in[2];
    const float* bq   = (const float*)d_in[3];
    const float* Wk   = (const float*)d_in[4];
    const float* bk   = (const float*)d_in[5];
    const float* Wv   = (const float*)d_in[6];
    const float* bv   = (const float*)d_in[7];
    float* out = (float*)d_out;

    // ws layout: [W^T bf16 x3 | q bf16 | k bf16 | v^T bf16 | ctrs(2 ints)]
    unsigned short* wt  = (unsigned short*)d_ws;                  // 3*128*128
    unsigned short* qws = (unsigned short*)((char*)d_ws + 98304);
    unsigned short* kws = qws + (size_t)B_ * N_ * D_;
    unsigned short* vtws = kws + (size_t)B_ * N_ * D_;
    int* ctr = (int*)((char*)d_ws + 98304 + 3 * (size_t)B_ * N_ * D_ * 2);

    hipMemsetAsync(ctr, 0, 8, stream);   // item counter + gbar counter
    mega_kernel<<<256, 512, 0, stream>>>(x, Wq, bq, Wk, bk, Wv, bv, vlen,
                                         wt, qws, kws, vtws, out, ctr);
}